// Round 2
// baseline (521.497 us; speedup 1.0000x reference)
//
#include <hip/hip_runtime.h>
#include <hip/hip_bf16.h>
#include <stdint.h>
#include <stddef.h>

// Problem constants
#define B_   2
#define N_   2048
#define D_   1024
#define H_   16
#define HD_  64
#define BH_  (B_ * H_)      // 32
#define M_   (B_ * N_)      // 4096 rows

typedef short bf16x8 __attribute__((ext_vector_type(8)));
typedef float f32x4  __attribute__((ext_vector_type(4)));

static __device__ __forceinline__ unsigned short f2bf(float f) {
    union { float f; unsigned u; } c; c.f = f;
    unsigned r = (c.u + 0x7FFFu + ((c.u >> 16) & 1u)) >> 16;
    return (unsigned short)r;
}
static __device__ __forceinline__ float bf2f(unsigned short u) {
    union { unsigned u; float f; } c; c.u = ((unsigned)u) << 16; return c.f;
}

// async global->LDS, 16B per lane; LDS dest = wave-uniform base + lane*16
#define GLDS16(g, l)                                                                     \
    __builtin_amdgcn_global_load_lds((const __attribute__((address_space(1))) void*)(g), \
                                     (__attribute__((address_space(3))) void*)(l), 16, 0, 0)

// ---------------- cast kernels ----------------
__global__ __launch_bounds__(256) void k_cast(const float* __restrict__ in,
                                              unsigned short* __restrict__ out, int n) {
    int i = (blockIdx.x * 256 + threadIdx.x) * 4;
    if (i >= n) return;
    float4 v = *(const float4*)(in + i);
    ushort4 o;
    o.x = f2bf(v.x); o.y = f2bf(v.y); o.z = f2bf(v.z); o.w = f2bf(v.w);
    *(ushort4*)(out + i) = o;
}

// descriptor fp32 [4096,1024] -> bf16 into cat[:, 0:1024] (ld 2048)
__global__ __launch_bounds__(256) void k_cast_desc(const float* __restrict__ in,
                                                   unsigned short* __restrict__ cat) {
    int i = (blockIdx.x * 256 + threadIdx.x) * 4;   // i < 4194304
    float4 v = *(const float4*)(in + i);
    int row = i >> 10, col = i & 1023;
    ushort4 o;
    o.x = f2bf(v.x); o.y = f2bf(v.y); o.z = f2bf(v.z); o.w = f2bf(v.w);
    *(ushort4*)(cat + (size_t)row * 2048 + col) = o;
}

// ---------------- GEMM: C[M,N] = A[M,K] * Bm[N,K]^T + bias ----------------
// m97 structure: 128x128 tile, BK=64, 4 waves, 16x16x32 bf16 MFMA, global_load_lds staging.
// EPI: 1 = bf16 store, 2 = fp32 store + residual add, 3 = qkv split-scatter (bf16)
template <int EPI>
__global__ __launch_bounds__(256) void k_gemm(const unsigned short* __restrict__ A, int lda,
                                              const unsigned short* __restrict__ Bm, int ldb,
                                              void* __restrict__ Cv, int ldc,
                                              const float* __restrict__ bias,
                                              const float* __restrict__ resid, int ldr,
                                              unsigned short* __restrict__ qd,
                                              unsigned short* __restrict__ kd,
                                              unsigned short* __restrict__ vd,
                                              int K) {
    __shared__ unsigned short As[128 * 64];
    __shared__ unsigned short Bs[128 * 64];
    const int tid  = threadIdx.x;
    const int wave = tid >> 6, lane = tid & 63;
    const int wr = wave >> 1, wc = wave & 1;
    const int brow = blockIdx.y * 128, bcol = blockIdx.x * 128;

    const int srow = (lane >> 3);        // staging row-within-8
    const int scol = (lane & 7) * 8;     // staging element offset in row
    const int frow = lane & 15;          // fragment row/col (lane&15)
    const int fk   = (lane >> 4) * 8;    // fragment k base

    f32x4 acc[4][4] = {};

    for (int kt = 0; kt < K; kt += 64) {
        __syncthreads();
#pragma unroll
        for (int j = 0; j < 4; ++j) {
            int r = wave * 32 + j * 8 + srow;
            GLDS16(A  + (size_t)(brow + r) * lda + kt + scol, (char*)As + wave * 4096 + j * 1024);
            GLDS16(Bm + (size_t)(bcol + r) * ldb + kt + scol, (char*)Bs + wave * 4096 + j * 1024);
        }
        __syncthreads();
#pragma unroll
        for (int ks = 0; ks < 2; ++ks) {
            bf16x8 a[4], b[4];
#pragma unroll
            for (int m = 0; m < 4; ++m)
                a[m] = *(const bf16x8*)(As + (wr * 64 + m * 16 + frow) * 64 + ks * 32 + fk);
#pragma unroll
            for (int n = 0; n < 4; ++n)
                b[n] = *(const bf16x8*)(Bs + (wc * 64 + n * 16 + frow) * 64 + ks * 32 + fk);
#pragma unroll
            for (int m = 0; m < 4; ++m)
#pragma unroll
                for (int n = 0; n < 4; ++n)
                    acc[m][n] = __builtin_amdgcn_mfma_f32_16x16x32_bf16(a[m], b[n], acc[m][n], 0, 0, 0);
        }
    }

    // epilogue: C/D layout col=lane&15, row=(lane>>4)*4+r
    const int orow = (lane >> 4) * 4;
#pragma unroll
    for (int m = 0; m < 4; ++m) {
        int row0 = brow + wr * 64 + m * 16 + orow;
#pragma unroll
        for (int n = 0; n < 4; ++n) {
            int col = bcol + wc * 64 + n * 16 + frow;
            float bs = bias[col];
#pragma unroll
            for (int r = 0; r < 4; ++r) {
                float v = acc[m][n][r] + bs;
                if (EPI == 3) {
                    // col in [0,3072) interpreted as h*192 + d*3 + c (H,HD,3 layout)
                    int row = row0 + r;
                    int bb = row >> 11, nr = row & (N_ - 1);
                    int h = col / 192;
                    int rem = col - h * 192;
                    int d = rem / 3;
                    int c = rem - d * 3;
                    unsigned short* dst = (c == 0) ? qd : (c == 1) ? kd : vd;
                    dst[(((size_t)(bb * H_ + h)) * N_ + nr) * 64 + d] = f2bf(v);
                } else if (EPI == 2) {
                    v += resid[(size_t)(row0 + r) * ldr + col];
                    ((float*)Cv)[(size_t)(row0 + r) * ldc + col] = v;
                } else {
                    ((unsigned short*)Cv)[(size_t)(row0 + r) * ldc + col] = f2bf(v);
                }
            }
        }
    }
}

// ---------------- in-place RoPE on Q,K (bf16), enc fp32 [2,B,H,N,HD] ----------------
__global__ __launch_bounds__(256) void k_rope_ip(unsigned short* __restrict__ Qb,
                                                 unsigned short* __restrict__ Kb,
                                                 const float* __restrict__ enc) {
    int idx = blockIdx.x * 256 + threadIdx.x;   // 2^21 pair-slots
    int i  = idx & 31;                // pair within head (d = 2i, 2i+1)
    int n  = (idx >> 5) & (N_ - 1);
    int bh = idx >> 16;
    size_t eoff = ((size_t)bh * N_ + n) * 64 + i * 2;
    float2 e0 = *(const float2*)(enc + eoff);
    float2 e1 = *(const float2*)(enc + (size_t)BH_ * N_ * 64 + eoff);
    ushort2 qp = *(const ushort2*)(Qb + eoff);
    ushort2 kp = *(const ushort2*)(Kb + eoff);
    float q1 = bf2f(qp.x), q2 = bf2f(qp.y);
    float k1 = bf2f(kp.x), k2 = bf2f(kp.y);
    // out[2i] = x[2i]*e0[2i] - x[2i+1]*e1[2i]; out[2i+1] = x[2i+1]*e0[2i+1] + x[2i]*e1[2i+1]
    ushort2 qo, ko;
    qo.x = f2bf(q1 * e0.x - q2 * e1.x);
    qo.y = f2bf(q2 * e0.y + q1 * e1.y);
    ko.x = f2bf(k1 * e0.x - k2 * e1.x);
    ko.y = f2bf(k2 * e0.y + k1 * e1.y);
    *(ushort2*)(Qb + eoff) = qo;
    *(ushort2*)(Kb + eoff) = ko;
}

// ---------------- V transpose: [B,H,N,HD] -> [B,H,HD,N] ----------------
__global__ __launch_bounds__(256) void k_transpose_v(const unsigned short* __restrict__ Vb,
                                                     unsigned short* __restrict__ Vt) {
    __shared__ unsigned short t[64][72];   // +8 pad
    int bh = blockIdx.y, n0 = blockIdx.x * 64;
    int tid = threadIdx.x;
    int r  = tid >> 2;            // 0..63 (n_local)
    int c0 = (tid & 3) * 16;      // 16 d per thread
    const unsigned short* src = Vb + ((size_t)bh * N_ + n0 + r) * 64 + c0;
    *(bf16x8*)(&t[r][c0])     = *(const bf16x8*)(src);
    *(bf16x8*)(&t[r][c0 + 8]) = *(const bf16x8*)(src + 8);
    __syncthreads();
    int d  = tid >> 2;            // 0..63
    int nc = (tid & 3) * 16;      // 16 n per thread
    bf16x8 o0, o1;
#pragma unroll
    for (int j = 0; j < 8; ++j) { o0[j] = (short)t[nc + j][d]; o1[j] = (short)t[nc + 8 + j][d]; }
    unsigned short* dst = Vt + ((size_t)bh * 64 + d) * N_ + n0 + nc;
    *(bf16x8*)(dst)     = o0;
    *(bf16x8*)(dst + 8) = o1;
}

// ---------------- flash attention ----------------
// grid (N/64, BH), 4 waves x 16 q-rows. K-tile/V-tile 64 keys in LDS.
__global__ __launch_bounds__(256) void k_attn(const unsigned short* __restrict__ Qb,
                                              const unsigned short* __restrict__ Kb,
                                              const unsigned short* __restrict__ Vt,
                                              unsigned short* __restrict__ Ctx) {
    __shared__ unsigned short Ks[64 * 64];    // [key][d]
    __shared__ unsigned short Vs[64 * 64];    // [d][key]
    __shared__ unsigned short Ps[4][16 * 64]; // per-wave P [q][key]
    int bh = blockIdx.y;
    int b = bh >> 4, h = bh & 15;
    int q0 = blockIdx.x * 64;
    int tid = threadIdx.x, wave = tid >> 6, lane = tid & 63;
    int frow = lane & 15, fk = (lane >> 4) * 8, g = lane >> 4;

    // Q fragments in registers (A-frag: row=lane&15, k=(lane>>4)*8+j)
    const unsigned short* qptr = Qb + ((size_t)bh * N_ + q0 + wave * 16 + frow) * 64;
    bf16x8 qf[2];
    qf[0] = *(const bf16x8*)(qptr + fk);
    qf[1] = *(const bf16x8*)(qptr + 32 + fk);

    float mrow[4] = {-INFINITY, -INFINITY, -INFINITY, -INFINITY};
    float lrow[4] = {0.f, 0.f, 0.f, 0.f};
    f32x4 accO[4] = {};

    for (int kt = 0; kt < N_; kt += 64) {
        __syncthreads();
#pragma unroll
        for (int j = 0; j < 2; ++j) {
            int r = wave * 16 + j * 8 + (lane >> 3);
            GLDS16(Kb + ((size_t)bh * N_ + kt + r) * 64 + (lane & 7) * 8,
                   (char*)Ks + wave * 2048 + j * 1024);
            GLDS16(Vt + ((size_t)bh * 64 + r) * N_ + kt + (lane & 7) * 8,
                   (char*)Vs + wave * 2048 + j * 1024);
        }
        __syncthreads();

        // S = (Q K^T) * 1/8 ; S layout: col=key=lane&15 (+kc*16), row=q=(lane>>4)*4+r
        f32x4 s[4];
#pragma unroll
        for (int kc = 0; kc < 4; ++kc) {
            f32x4 a = {};
#pragma unroll
            for (int ks = 0; ks < 2; ++ks) {
                bf16x8 kfr = *(const bf16x8*)(Ks + (kc * 16 + frow) * 64 + ks * 32 + fk);
                a = __builtin_amdgcn_mfma_f32_16x16x32_bf16(qf[ks], kfr, a, 0, 0, 0);
            }
            s[kc] = a * 0.125f;
        }

        // online softmax (per q-row: 16-lane group with same g, reg r)
        float scl[4];
#pragma unroll
        for (int r = 0; r < 4; ++r) {
            float mx = fmaxf(fmaxf(s[0][r], s[1][r]), fmaxf(s[2][r], s[3][r]));
            mx = fmaxf(mx, __shfl_xor(mx, 1));
            mx = fmaxf(mx, __shfl_xor(mx, 2));
            mx = fmaxf(mx, __shfl_xor(mx, 4));
            mx = fmaxf(mx, __shfl_xor(mx, 8));
            float mn = fmaxf(mrow[r], mx);
            float sc = __expf(mrow[r] - mn);
            mrow[r] = mn;
            float ps = 0.f;
#pragma unroll
            for (int kc = 0; kc < 4; ++kc) {
                float p = __expf(s[kc][r] - mn);
                s[kc][r] = p;
                ps += p;
            }
            ps += __shfl_xor(ps, 1);
            ps += __shfl_xor(ps, 2);
            ps += __shfl_xor(ps, 4);
            ps += __shfl_xor(ps, 8);
            lrow[r] = lrow[r] * sc + ps;
            scl[r] = sc;
        }
#pragma unroll
        for (int df = 0; df < 4; ++df)
#pragma unroll
            for (int r = 0; r < 4; ++r) accO[df][r] *= scl[r];

        // stage P to LDS (acc layout -> A-frag layout)
#pragma unroll
        for (int kc = 0; kc < 4; ++kc)
#pragma unroll
            for (int r = 0; r < 4; ++r)
                Ps[wave][(g * 4 + r) * 64 + kc * 16 + frow] = f2bf(s[kc][r]);
        asm volatile("s_waitcnt lgkmcnt(0)" ::: "memory");
        __builtin_amdgcn_sched_barrier(0);

        // O += P V
#pragma unroll
        for (int ks = 0; ks < 2; ++ks) {
            bf16x8 pa = *(const bf16x8*)(&Ps[wave][frow * 64 + ks * 32 + fk]);
#pragma unroll
            for (int df = 0; df < 4; ++df) {
                bf16x8 vf = *(const bf16x8*)(Vs + (df * 16 + frow) * 64 + ks * 32 + fk);
                accO[df] = __builtin_amdgcn_mfma_f32_16x16x32_bf16(pa, vf, accO[df], 0, 0, 0);
            }
        }
    }

    // write context into [B, N, H*HD] (bf16)
#pragma unroll
    for (int df = 0; df < 4; ++df)
#pragma unroll
        for (int r = 0; r < 4; ++r) {
            int q = q0 + wave * 16 + g * 4 + r;
            float v = accO[df][r] / lrow[r];
            Ctx[((size_t)(b * N_ + q)) * D_ + h * 64 + df * 16 + frow] = f2bf(v);
        }
}

// ---------------- LayerNorm + exact GELU (per row of 2048, bf16 in/out) ----------------
__global__ __launch_bounds__(256) void k_ln_gelu(const unsigned short* __restrict__ hsrc,
                                                 const float* __restrict__ gma,
                                                 const float* __restrict__ bta,
                                                 unsigned short* __restrict__ out) {
    __shared__ float red[2][4];
    int row = blockIdx.x, tid = threadIdx.x;
    const unsigned short* hr = hsrc + (size_t)row * 2048 + tid * 8;
    bf16x8 hv = *(const bf16x8*)(hr);
    float xs[8];
    float s = 0.f, q = 0.f;
#pragma unroll
    for (int j = 0; j < 8; ++j) {
        float x = bf2f((unsigned short)hv[j]);
        xs[j] = x; s += x; q += x * x;
    }
#pragma unroll
    for (int off = 1; off < 64; off <<= 1) {
        s += __shfl_xor(s, off);
        q += __shfl_xor(q, off);
    }
    int wave = tid >> 6;
    if ((tid & 63) == 0) { red[0][wave] = s; red[1][wave] = q; }
    __syncthreads();
    s = red[0][0] + red[0][1] + red[0][2] + red[0][3];
    q = red[1][0] + red[1][1] + red[1][2] + red[1][3];
    float mu   = s * (1.f / 2048.f);
    float var  = q * (1.f / 2048.f) - mu * mu;
    float rstd = rsqrtf(var + 1e-5f);
    int c = tid * 8;
#pragma unroll
    for (int j = 0; j < 8; ++j) {
        float x = (xs[j] - mu) * rstd * gma[c + j] + bta[c + j];
        float y = 0.5f * x * (1.f + erff(x * 0.70710678118654752f));
        out[(size_t)row * 2048 + c + j] = f2bf(y);
    }
}

// ---------------- launch ----------------
extern "C" void kernel_launch(void* const* d_in, const int* in_sizes, int n_in,
                              void* d_out, int out_size, void* d_ws, size_t ws_size,
                              hipStream_t stream) {
    const float* descriptor = (const float*)d_in[0];
    const float* encoding   = (const float*)d_in[1];
    const float* w_qkv      = (const float*)d_in[2];
    const float* b_qkv      = (const float*)d_in[3];
    const float* w_out      = (const float*)d_in[4];
    const float* b_out      = (const float*)d_in[5];
    const float* w_ffn1     = (const float*)d_in[6];
    const float* b_ffn1     = (const float*)d_in[7];
    const float* ln_g       = (const float*)d_in[8];
    const float* ln_b       = (const float*)d_in[9];
    const float* w_ffn2     = (const float*)d_in[10];
    const float* b_ffn2     = (const float*)d_in[11];
    float* out = (float*)d_out;

    char* ws = (char*)d_ws;
    // Tight 62MB layout with liveness-based aliasing:
    unsigned short* wffn1_b = (unsigned short*)(ws);                        // [0,8)
    unsigned short* wffn2_b = (unsigned short*)(ws + ((size_t)8  << 20));   // [8,12)
    unsigned short* wout_b  = (unsigned short*)(ws + ((size_t)12 << 20));   // [12,14)
    unsigned short* cat     = (unsigned short*)(ws + ((size_t)14 << 20));   // [14,30) live: ->FFN1
    unsigned short* Qb      = (unsigned short*)(ws + ((size_t)30 << 20));   // [30,38) live: qkv->attn
    unsigned short* Kb      = (unsigned short*)(ws + ((size_t)38 << 20));   // [38,46)
    unsigned short* Vb      = (unsigned short*)(ws + ((size_t)46 << 20));   // [46,54) live: qkv->transpose
    unsigned short* wqkv_b  = (unsigned short*)(ws + ((size_t)54 << 20));   // [54,60) live: ->qkv gemm
    unsigned short* Vt      = (unsigned short*)(ws + ((size_t)54 << 20));   // [54,62) after qkv gemm
    unsigned short* msg     = (unsigned short*)(ws + ((size_t)46 << 20));   // over Vb (dead after transpose)
    unsigned short* hbuf    = (unsigned short*)(ws + ((size_t)30 << 20));   // over Qb/Kb (dead after attn)
    unsigned short* h2      = (unsigned short*)(ws + ((size_t)14 << 20));   // over cat (dead after FFN1)

    // 1) casts
    k_cast_desc<<<4096, 256, 0, stream>>>(descriptor, cat);
    k_cast<<<3072, 256, 0, stream>>>(w_qkv, wqkv_b, 3145728);
    k_cast<<<1024, 256, 0, stream>>>(w_out, wout_b, 1048576);
    k_cast<<<4096, 256, 0, stream>>>(w_ffn1, wffn1_b, 4194304);
    k_cast<<<2048, 256, 0, stream>>>(w_ffn2, wffn2_b, 2097152);

    // 2) QKV projection with split-scatter epilogue -> Qb,Kb,Vb bf16 [B,H,N,64]
    k_gemm<3><<<dim3(24, 32), 256, 0, stream>>>(cat, 2048, wqkv_b, 1024, nullptr, 0,
                                                b_qkv, nullptr, 0, Qb, Kb, Vb, 1024);
    // 3) in-place RoPE on Q,K
    k_rope_ip<<<8192, 256, 0, stream>>>(Qb, Kb, encoding);
    // 4) V transpose -> [B,H,64,N]
    k_transpose_v<<<dim3(32, 32), 256, 0, stream>>>(Vb, Vt);
    // 5) attention -> msg bf16 [4096,1024]
    k_attn<<<dim3(32, 32), 256, 0, stream>>>(Qb, Kb, Vt, msg);
    // 6) out-proj -> bf16 into cat[:,1024:2048]
    k_gemm<1><<<dim3(8, 32), 256, 0, stream>>>(msg, 1024, wout_b, 1024, cat + 1024, 2048,
                                               b_out, nullptr, 0, nullptr, nullptr, nullptr, 1024);
    // 7) FFN1: cat [4096,2048] @ w_ffn1^T -> hbuf bf16
    k_gemm<1><<<dim3(16, 32), 256, 0, stream>>>(cat, 2048, wffn1_b, 2048, hbuf, 2048,
                                                b_ffn1, nullptr, 0, nullptr, nullptr, nullptr, 2048);
    // 8) LayerNorm + GELU -> h2 bf16
    k_ln_gelu<<<4096, 256, 0, stream>>>(hbuf, ln_g, ln_b, h2);
    // 9) FFN2 + residual -> out f32
    k_gemm<2><<<dim3(8, 32), 256, 0, stream>>>(h2, 2048, wffn2_b, 2048, out, 1024,
                                               b_ffn2, descriptor, 1024, nullptr, nullptr, nullptr, 2048);
}

// Round 3
// 482.112 us; speedup vs baseline: 1.0817x; 1.0817x over previous
//
#include <hip/hip_runtime.h>
#include <hip/hip_bf16.h>
#include <stdint.h>
#include <stddef.h>

// Problem constants
#define B_   2
#define N_   2048
#define D_   1024
#define H_   16
#define HD_  64
#define BH_  (B_ * H_)      // 32
#define M_   (B_ * N_)      // 4096 rows

typedef short bf16x8 __attribute__((ext_vector_type(8)));
typedef float f32x4  __attribute__((ext_vector_type(4)));

static __device__ __forceinline__ unsigned short f2bf(float f) {
    union { float f; unsigned u; } c; c.f = f;
    unsigned r = (c.u + 0x7FFFu + ((c.u >> 16) & 1u)) >> 16;
    return (unsigned short)r;
}
static __device__ __forceinline__ float bf2f(unsigned short u) {
    union { unsigned u; float f; } c; c.u = ((unsigned)u) << 16; return c.f;
}

// async global->LDS, 16B per lane; LDS dest = wave-uniform base + lane*16
#define GLDS16(g, l)                                                                     \
    __builtin_amdgcn_global_load_lds((const __attribute__((address_space(1))) void*)(g), \
                                     (__attribute__((address_space(3))) void*)(l), 16, 0, 0)

// Q pre-scale: 1/sqrt(64) * log2(e), so attention uses native exp2
#define QSCALE 0.18033688011112042f

// ---------------- cast kernels ----------------
// fused 4-weight cast (w_qkv 3M, w_out 1M, w_ffn1 4M, w_ffn2 2M floats)
__global__ __launch_bounds__(256) void k_cast_w4(const float* __restrict__ s0,
                                                 const float* __restrict__ s1,
                                                 const float* __restrict__ s2,
                                                 const float* __restrict__ s3,
                                                 unsigned short* __restrict__ d0,
                                                 unsigned short* __restrict__ d1,
                                                 unsigned short* __restrict__ d2,
                                                 unsigned short* __restrict__ d3) {
    int i = blockIdx.x * 256 + threadIdx.x;   // vec4 index, total 2621440
    const float* s; unsigned short* d; int off;
    if (i < 786432)              { s = s0; d = d0; off = i; }
    else if (i < 1048576)        { s = s1; d = d1; off = i - 786432; }
    else if (i < 2097152)        { s = s2; d = d2; off = i - 1048576; }
    else                         { s = s3; d = d3; off = i - 2097152; }
    float4 v = *(const float4*)(s + (size_t)off * 4);
    ushort4 o;
    o.x = f2bf(v.x); o.y = f2bf(v.y); o.z = f2bf(v.z); o.w = f2bf(v.w);
    *(ushort4*)(d + (size_t)off * 4) = o;
}

// descriptor fp32 [4096,1024] -> bf16 into cat[:, 0:1024] (ld 2048)
__global__ __launch_bounds__(256) void k_cast_desc(const float* __restrict__ in,
                                                   unsigned short* __restrict__ cat) {
    int i = (blockIdx.x * 256 + threadIdx.x) * 4;   // i < 4194304
    float4 v = *(const float4*)(in + i);
    int row = i >> 10, col = i & 1023;
    ushort4 o;
    o.x = f2bf(v.x); o.y = f2bf(v.y); o.z = f2bf(v.z); o.w = f2bf(v.w);
    *(ushort4*)(cat + (size_t)row * 2048 + col) = o;
}

// ---------------- GEMM: C[M,N] = A[M,K] * Bm[N,K]^T + bias ----------------
// m97 structure: 128x128 tile, BK=64, 4 waves, 16x16x32 bf16 MFMA, global_load_lds staging.
// EPI: 1 = bf16 store, 2 = fp32 store + residual add, 3 = qkv split-scatter (bf16)
template <int EPI>
__global__ __launch_bounds__(256) void k_gemm(const unsigned short* __restrict__ A, int lda,
                                              const unsigned short* __restrict__ Bm, int ldb,
                                              void* __restrict__ Cv, int ldc,
                                              const float* __restrict__ bias,
                                              const float* __restrict__ resid, int ldr,
                                              unsigned short* __restrict__ qd,
                                              unsigned short* __restrict__ kd,
                                              unsigned short* __restrict__ vd,
                                              int K) {
    __shared__ unsigned short As[128 * 64];
    __shared__ unsigned short Bs[128 * 64];
    const int tid  = threadIdx.x;
    const int wave = tid >> 6, lane = tid & 63;
    const int wr = wave >> 1, wc = wave & 1;
    const int brow = blockIdx.y * 128, bcol = blockIdx.x * 128;

    const int srow = (lane >> 3);        // staging row-within-8
    const int scol = (lane & 7) * 8;     // staging element offset in row
    const int frow = lane & 15;          // fragment row/col (lane&15)
    const int fk   = (lane >> 4) * 8;    // fragment k base

    f32x4 acc[4][4] = {};

    for (int kt = 0; kt < K; kt += 64) {
        __syncthreads();
#pragma unroll
        for (int j = 0; j < 4; ++j) {
            int r = wave * 32 + j * 8 + srow;
            GLDS16(A  + (size_t)(brow + r) * lda + kt + scol, (char*)As + wave * 4096 + j * 1024);
            GLDS16(Bm + (size_t)(bcol + r) * ldb + kt + scol, (char*)Bs + wave * 4096 + j * 1024);
        }
        __syncthreads();
#pragma unroll
        for (int ks = 0; ks < 2; ++ks) {
            bf16x8 a[4], b[4];
#pragma unroll
            for (int m = 0; m < 4; ++m)
                a[m] = *(const bf16x8*)(As + (wr * 64 + m * 16 + frow) * 64 + ks * 32 + fk);
#pragma unroll
            for (int n = 0; n < 4; ++n)
                b[n] = *(const bf16x8*)(Bs + (wc * 64 + n * 16 + frow) * 64 + ks * 32 + fk);
#pragma unroll
            for (int m = 0; m < 4; ++m)
#pragma unroll
                for (int n = 0; n < 4; ++n)
                    acc[m][n] = __builtin_amdgcn_mfma_f32_16x16x32_bf16(a[m], b[n], acc[m][n], 0, 0, 0);
        }
    }

    // epilogue: C/D layout col=lane&15, row=(lane>>4)*4+r
    const int orow = (lane >> 4) * 4;
#pragma unroll
    for (int m = 0; m < 4; ++m) {
        int row0 = brow + wr * 64 + m * 16 + orow;
#pragma unroll
        for (int n = 0; n < 4; ++n) {
            int col = bcol + wc * 64 + n * 16 + frow;
            float bs = bias[col];
#pragma unroll
            for (int r = 0; r < 4; ++r) {
                float v = acc[m][n][r] + bs;
                if (EPI == 3) {
                    // col in [0,3072) interpreted as h*192 + d*3 + c (H,HD,3 layout)
                    int row = row0 + r;
                    int bb = row >> 11, nr = row & (N_ - 1);
                    int h = col / 192;
                    int rem = col - h * 192;
                    int d = rem / 3;
                    int c = rem - d * 3;
                    unsigned short* dst = (c == 0) ? qd : (c == 1) ? kd : vd;
                    dst[(((size_t)(bb * H_ + h)) * N_ + nr) * 64 + d] = f2bf(v);
                } else if (EPI == 2) {
                    v += resid[(size_t)(row0 + r) * ldr + col];
                    ((float*)Cv)[(size_t)(row0 + r) * ldc + col] = v;
                } else {
                    ((unsigned short*)Cv)[(size_t)(row0 + r) * ldc + col] = f2bf(v);
                }
            }
        }
    }
}

// ---------------- in-place RoPE on Q,K (bf16), enc fp32 [2,B,H,N,HD] ----------------
// Q additionally pre-scaled by QSCALE so attention can use exp2 directly.
__global__ __launch_bounds__(256) void k_rope_ip(unsigned short* __restrict__ Qb,
                                                 unsigned short* __restrict__ Kb,
                                                 const float* __restrict__ enc) {
    int idx = blockIdx.x * 256 + threadIdx.x;   // 2^21 pair-slots
    int i  = idx & 31;                // pair within head (d = 2i, 2i+1)
    int n  = (idx >> 5) & (N_ - 1);
    int bh = idx >> 16;
    size_t eoff = ((size_t)bh * N_ + n) * 64 + i * 2;
    float2 e0 = *(const float2*)(enc + eoff);
    float2 e1 = *(const float2*)(enc + (size_t)BH_ * N_ * 64 + eoff);
    ushort2 qp = *(const ushort2*)(Qb + eoff);
    ushort2 kp = *(const ushort2*)(Kb + eoff);
    float q1 = bf2f(qp.x), q2 = bf2f(qp.y);
    float k1 = bf2f(kp.x), k2 = bf2f(kp.y);
    ushort2 qo, ko;
    qo.x = f2bf((q1 * e0.x - q2 * e1.x) * QSCALE);
    qo.y = f2bf((q2 * e0.y + q1 * e1.y) * QSCALE);
    ko.x = f2bf(k1 * e0.x - k2 * e1.x);
    ko.y = f2bf(k2 * e0.y + k1 * e1.y);
    *(ushort2*)(Qb + eoff) = qo;
    *(ushort2*)(Kb + eoff) = ko;
}

// ---------------- V transpose: [B,H,N,HD] -> [B,H,HD,N] ----------------
__global__ __launch_bounds__(256) void k_transpose_v(const unsigned short* __restrict__ Vb,
                                                     unsigned short* __restrict__ Vt) {
    __shared__ unsigned short t[64][72];   // +8 pad
    int bh = blockIdx.y, n0 = blockIdx.x * 64;
    int tid = threadIdx.x;
    int r  = tid >> 2;            // 0..63 (n_local)
    int c0 = (tid & 3) * 16;      // 16 d per thread
    const unsigned short* src = Vb + ((size_t)bh * N_ + n0 + r) * 64 + c0;
    *(bf16x8*)(&t[r][c0])     = *(const bf16x8*)(src);
    *(bf16x8*)(&t[r][c0 + 8]) = *(const bf16x8*)(src + 8);
    __syncthreads();
    int d  = tid >> 2;            // 0..63
    int nc = (tid & 3) * 16;      // 16 n per thread
    bf16x8 o0, o1;
#pragma unroll
    for (int j = 0; j < 8; ++j) { o0[j] = (short)t[nc + j][d]; o1[j] = (short)t[nc + 8 + j][d]; }
    unsigned short* dst = Vt + ((size_t)bh * 64 + d) * N_ + n0 + nc;
    *(bf16x8*)(dst)     = o0;
    *(bf16x8*)(dst + 8) = o1;
}

// ---------------- flash attention ----------------
// grid 1024 blocks, XCD-swizzled so each bh's K/V lives in one XCD's L2.
// 4 waves x 16 q-rows (QBLK=64), KV tile 64 keys, double-buffered LDS with
// XOR-swizzled layout (elem_col ^= (row&7)*8) on Ks/Vs/Ps.
__global__ __launch_bounds__(256) void k_attn(const unsigned short* __restrict__ Qb,
                                              const unsigned short* __restrict__ Kb,
                                              const unsigned short* __restrict__ Vt,
                                              unsigned short* __restrict__ Ctx) {
    __shared__ unsigned short Ks[2][64 * 64];  // [key][d], swizzled
    __shared__ unsigned short Vs[2][64 * 64];  // [d][key], swizzled
    __shared__ unsigned short Ps[4][16 * 64];  // per-wave P [q][key], swizzled

    // XCD-aware remap: lin%8 = XCD; give each XCD 4 whole bh (512KB K+V < 4MB L2)
    int lin = blockIdx.x + 32 * blockIdx.y;   // 0..1023
    int ixc = lin >> 3;                        // 0..127 within-XCD index
    int bh  = (lin & 7) * 4 + (ixc >> 5);
    int q0  = (ixc & 31) * 64;
    int b = bh >> 4, h = bh & 15;
    int tid = threadIdx.x, wave = tid >> 6, lane = tid & 63;
    int frow = lane & 15, fk = (lane >> 4) * 8, g = lane >> 4;
    int f7x8 = (frow & 7) * 8;                 // read-side swizzle term

    // staging: per wave 16 rows (8 lanes/row), source col pre-swizzled so that
    // LDS[row][c] = global[row][c ^ ((row&7)*8)]
    int srow = lane >> 3;                          // 0..7 == row&7
    int scol = ((lane & 7) ^ srow) * 8;            // swizzled source col (elems)

    const unsigned short* Kbh = Kb + (size_t)bh * N_ * 64;
    const unsigned short* Vbh = Vt + (size_t)bh * 64 * N_;

#define ATTN_STAGE(bufi, kt)                                                           \
    do {                                                                               \
        _Pragma("unroll")                                                              \
        for (int j = 0; j < 2; ++j) {                                                  \
            int rr = wave * 16 + j * 8 + srow;                                         \
            GLDS16(Kbh + (size_t)((kt) + rr) * 64 + scol,                              \
                   (char*)Ks[bufi] + wave * 2048 + j * 1024);                          \
            GLDS16(Vbh + (size_t)rr * N_ + (kt) + scol,                                \
                   (char*)Vs[bufi] + wave * 2048 + j * 1024);                          \
        }                                                                              \
    } while (0)

    // Q fragments in registers (A-frag: row=lane&15, k=(lane>>4)*8+j)
    const unsigned short* qptr = Qb + ((size_t)bh * N_ + q0 + wave * 16 + frow) * 64;
    bf16x8 qf[2];
    qf[0] = *(const bf16x8*)(qptr + fk);
    qf[1] = *(const bf16x8*)(qptr + 32 + fk);

    float mrow[4] = {-INFINITY, -INFINITY, -INFINITY, -INFINITY};
    float lrow[4] = {0.f, 0.f, 0.f, 0.f};
    f32x4 accO[4] = {};

    ATTN_STAGE(0, 0);

    for (int t = 0; t < N_ / 64; ++t) {
        int cur = t & 1;
        __syncthreads();                      // drains vmcnt: tile t resident
        if (t + 1 < N_ / 64) ATTN_STAGE(cur ^ 1, (t + 1) * 64);

        // S = Q K^T (Q pre-scaled); S layout: col=key=lane&15(+kc*16), row=q=g*4+r
        f32x4 s[4];
        __builtin_amdgcn_s_setprio(1);
#pragma unroll
        for (int kc = 0; kc < 4; ++kc) {
            f32x4 a = {};
#pragma unroll
            for (int ks = 0; ks < 2; ++ks) {
                bf16x8 kfr = *(const bf16x8*)(Ks[cur] + (kc * 16 + frow) * 64 + ((ks * 32 + fk) ^ f7x8));
                a = __builtin_amdgcn_mfma_f32_16x16x32_bf16(qf[ks], kfr, a, 0, 0, 0);
            }
            s[kc] = a;
        }
        __builtin_amdgcn_s_setprio(0);

        // online softmax in exp2 domain (per q-row: 16-lane group g, reg r)
        float scl[4];
#pragma unroll
        for (int r = 0; r < 4; ++r) {
            float mx = fmaxf(fmaxf(s[0][r], s[1][r]), fmaxf(s[2][r], s[3][r]));
            mx = fmaxf(mx, __shfl_xor(mx, 1));
            mx = fmaxf(mx, __shfl_xor(mx, 2));
            mx = fmaxf(mx, __shfl_xor(mx, 4));
            mx = fmaxf(mx, __shfl_xor(mx, 8));
            float mn = fmaxf(mrow[r], mx);
            float sc = exp2f(mrow[r] - mn);
            mrow[r] = mn;
            float ps = 0.f;
#pragma unroll
            for (int kc = 0; kc < 4; ++kc) {
                float p = exp2f(s[kc][r] - mn);
                s[kc][r] = p;
                ps += p;
            }
            ps += __shfl_xor(ps, 1);
            ps += __shfl_xor(ps, 2);
            ps += __shfl_xor(ps, 4);
            ps += __shfl_xor(ps, 8);
            lrow[r] = lrow[r] * sc + ps;
            scl[r] = sc;
        }
#pragma unroll
        for (int df = 0; df < 4; ++df)
#pragma unroll
            for (int r = 0; r < 4; ++r) accO[df][r] *= scl[r];

        // stage P to LDS (acc layout -> A-frag layout), swizzled
#pragma unroll
        for (int kc = 0; kc < 4; ++kc)
#pragma unroll
            for (int r = 0; r < 4; ++r) {
                int prow = g * 4 + r;
                Ps[wave][prow * 64 + ((kc * 16 + frow) ^ ((prow & 7) * 8))] = f2bf(s[kc][r]);
            }
        asm volatile("s_waitcnt lgkmcnt(0)" ::: "memory");
        __builtin_amdgcn_sched_barrier(0);

        // O += P V
        __builtin_amdgcn_s_setprio(1);
#pragma unroll
        for (int ks = 0; ks < 2; ++ks) {
            bf16x8 pa = *(const bf16x8*)(&Ps[wave][frow * 64 + ((ks * 32 + fk) ^ f7x8)]);
#pragma unroll
            for (int df = 0; df < 4; ++df) {
                bf16x8 vf = *(const bf16x8*)(Vs[cur] + (df * 16 + frow) * 64 + ((ks * 32 + fk) ^ f7x8));
                accO[df] = __builtin_amdgcn_mfma_f32_16x16x32_bf16(pa, vf, accO[df], 0, 0, 0);
            }
        }
        __builtin_amdgcn_s_setprio(0);
    }

    // write context into [B, N, H*HD] (bf16)
    float inv[4];
#pragma unroll
    for (int r = 0; r < 4; ++r) inv[r] = 1.0f / lrow[r];
#pragma unroll
    for (int df = 0; df < 4; ++df)
#pragma unroll
        for (int r = 0; r < 4; ++r) {
            int q = q0 + wave * 16 + g * 4 + r;
            Ctx[((size_t)(b * N_ + q)) * D_ + h * 64 + df * 16 + frow] = f2bf(accO[df][r] * inv[r]);
        }
#undef ATTN_STAGE
}

// ---------------- LayerNorm + exact GELU (per row of 2048, bf16 in/out) ----------------
__global__ __launch_bounds__(256) void k_ln_gelu(const unsigned short* __restrict__ hsrc,
                                                 const float* __restrict__ gma,
                                                 const float* __restrict__ bta,
                                                 unsigned short* __restrict__ out) {
    __shared__ float red[2][4];
    int row = blockIdx.x, tid = threadIdx.x;
    const unsigned short* hr = hsrc + (size_t)row * 2048 + tid * 8;
    bf16x8 hv = *(const bf16x8*)(hr);
    float xs[8];
    float s = 0.f, q = 0.f;
#pragma unroll
    for (int j = 0; j < 8; ++j) {
        float x = bf2f((unsigned short)hv[j]);
        xs[j] = x; s += x; q += x * x;
    }
#pragma unroll
    for (int off = 1; off < 64; off <<= 1) {
        s += __shfl_xor(s, off);
        q += __shfl_xor(q, off);
    }
    int wave = tid >> 6;
    if ((tid & 63) == 0) { red[0][wave] = s; red[1][wave] = q; }
    __syncthreads();
    s = red[0][0] + red[0][1] + red[0][2] + red[0][3];
    q = red[1][0] + red[1][1] + red[1][2] + red[1][3];
    float mu   = s * (1.f / 2048.f);
    float var  = q * (1.f / 2048.f) - mu * mu;
    float rstd = rsqrtf(var + 1e-5f);
    int c = tid * 8;
#pragma unroll
    for (int j = 0; j < 8; ++j) {
        float x = (xs[j] - mu) * rstd * gma[c + j] + bta[c + j];
        float y = 0.5f * x * (1.f + erff(x * 0.70710678118654752f));
        out[(size_t)row * 2048 + c + j] = f2bf(y);
    }
}

// ---------------- launch ----------------
extern "C" void kernel_launch(void* const* d_in, const int* in_sizes, int n_in,
                              void* d_out, int out_size, void* d_ws, size_t ws_size,
                              hipStream_t stream) {
    const float* descriptor = (const float*)d_in[0];
    const float* encoding   = (const float*)d_in[1];
    const float* w_qkv      = (const float*)d_in[2];
    const float* b_qkv      = (const float*)d_in[3];
    const float* w_out      = (const float*)d_in[4];
    const float* b_out      = (const float*)d_in[5];
    const float* w_ffn1     = (const float*)d_in[6];
    const float* b_ffn1     = (const float*)d_in[7];
    const float* ln_g       = (const float*)d_in[8];
    const float* ln_b       = (const float*)d_in[9];
    const float* w_ffn2     = (const float*)d_in[10];
    const float* b_ffn2     = (const float*)d_in[11];
    float* out = (float*)d_out;

    char* ws = (char*)d_ws;
    // Tight 62MB layout with liveness-based aliasing:
    unsigned short* wffn1_b = (unsigned short*)(ws);                        // [0,8)
    unsigned short* wffn2_b = (unsigned short*)(ws + ((size_t)8  << 20));   // [8,12)
    unsigned short* wout_b  = (unsigned short*)(ws + ((size_t)12 << 20));   // [12,14)
    unsigned short* cat     = (unsigned short*)(ws + ((size_t)14 << 20));   // [14,30) live: ->FFN1
    unsigned short* Qb      = (unsigned short*)(ws + ((size_t)30 << 20));   // [30,38) live: qkv->attn
    unsigned short* Kb      = (unsigned short*)(ws + ((size_t)38 << 20));   // [38,46)
    unsigned short* Vb      = (unsigned short*)(ws + ((size_t)46 << 20));   // [46,54) live: qkv->transpose
    unsigned short* wqkv_b  = (unsigned short*)(ws + ((size_t)54 << 20));   // [54,60) live: ->qkv gemm
    unsigned short* Vt      = (unsigned short*)(ws + ((size_t)54 << 20));   // [54,62) after qkv gemm
    unsigned short* msg     = (unsigned short*)(ws + ((size_t)46 << 20));   // over Vb (dead after transpose)
    unsigned short* hbuf    = (unsigned short*)(ws + ((size_t)30 << 20));   // over Qb/Kb (dead after attn)
    unsigned short* h2      = (unsigned short*)(ws + ((size_t)14 << 20));   // over cat (dead after FFN1)

    // 1) casts
    k_cast_desc<<<4096, 256, 0, stream>>>(descriptor, cat);
    k_cast_w4<<<10240, 256, 0, stream>>>(w_qkv, w_out, w_ffn1, w_ffn2,
                                         wqkv_b, wout_b, wffn1_b, wffn2_b);

    // 2) QKV projection with split-scatter epilogue -> Qb,Kb,Vb bf16 [B,H,N,64]
    k_gemm<3><<<dim3(24, 32), 256, 0, stream>>>(cat, 2048, wqkv_b, 1024, nullptr, 0,
                                                b_qkv, nullptr, 0, Qb, Kb, Vb, 1024);
    // 3) in-place RoPE on Q,K (Q pre-scaled by QSCALE)
    k_rope_ip<<<8192, 256, 0, stream>>>(Qb, Kb, encoding);
    // 4) V transpose -> [B,H,64,N]
    k_transpose_v<<<dim3(32, 32), 256, 0, stream>>>(Vb, Vt);
    // 5) attention -> msg bf16 [4096,1024]
    k_attn<<<dim3(32, 32), 256, 0, stream>>>(Qb, Kb, Vt, msg);
    // 6) out-proj -> bf16 into cat[:,1024:2048]
    k_gemm<1><<<dim3(8, 32), 256, 0, stream>>>(msg, 1024, wout_b, 1024, cat + 1024, 2048,
                                               b_out, nullptr, 0, nullptr, nullptr, nullptr, 1024);
    // 7) FFN1: cat [4096,2048] @ w_ffn1^T -> hbuf bf16
    k_gemm<1><<<dim3(16, 32), 256, 0, stream>>>(cat, 2048, wffn1_b, 2048, hbuf, 2048,
                                                b_ffn1, nullptr, 0, nullptr, nullptr, nullptr, 2048);
    // 8) LayerNorm + GELU -> h2 bf16
    k_ln_gelu<<<4096, 256, 0, stream>>>(hbuf, ln_g, ln_b, h2);
    // 9) FFN2 + residual -> out f32
    k_gemm<2><<<dim3(8, 32), 256, 0, stream>>>(h2, 2048, wffn2_b, 2048, out, 1024,
                                               b_ffn2, descriptor, 1024, nullptr, nullptr, nullptr, 2048);
}

// Round 6
// 455.093 us; speedup vs baseline: 1.1459x; 1.0594x over previous
//
#include <hip/hip_runtime.h>
#include <hip/hip_bf16.h>
#include <stdint.h>
#include <stddef.h>

// Problem constants
#define B_   2
#define N_   2048
#define D_   1024
#define H_   16
#define HD_  64
#define BH_  (B_ * H_)      // 32
#define M_   (B_ * N_)      // 4096 rows

typedef short bf16x8 __attribute__((ext_vector_type(8)));
typedef float f32x4  __attribute__((ext_vector_type(4)));

static __device__ __forceinline__ unsigned short f2bf(float f) {
    union { float f; unsigned u; } c; c.f = f;
    unsigned r = (c.u + 0x7FFFu + ((c.u >> 16) & 1u)) >> 16;
    return (unsigned short)r;
}
static __device__ __forceinline__ float bf2f(unsigned short u) {
    union { unsigned u; float f; } c; c.u = ((unsigned)u) << 16; return c.f;
}

// async global->LDS, 16B per lane; LDS dest = wave-uniform base + lane*16
#define GLDS16(g, l)                                                                     \
    __builtin_amdgcn_global_load_lds((const __attribute__((address_space(1))) void*)(g), \
                                     (__attribute__((address_space(3))) void*)(l), 16, 0, 0)

// Q pre-scale: 1/sqrt(64) * log2(e), so attention uses native exp2
#define QSCALE 0.18033688011112042f

// ---------------- cast kernels ----------------
// fused 4-weight cast (w_qkv 3M, w_out 1M, w_ffn1 4M, w_ffn2 2M floats)
__global__ __launch_bounds__(256) void k_cast_w4(const float* __restrict__ s0,
                                                 const float* __restrict__ s1,
                                                 const float* __restrict__ s2,
                                                 const float* __restrict__ s3,
                                                 unsigned short* __restrict__ d0,
                                                 unsigned short* __restrict__ d1,
                                                 unsigned short* __restrict__ d2,
                                                 unsigned short* __restrict__ d3) {
    int i = blockIdx.x * 256 + threadIdx.x;   // vec4 index, total 2621440
    const float* s; unsigned short* d; int off;
    if (i < 786432)              { s = s0; d = d0; off = i; }
    else if (i < 1048576)        { s = s1; d = d1; off = i - 786432; }
    else if (i < 2097152)        { s = s2; d = d2; off = i - 1048576; }
    else                         { s = s3; d = d3; off = i - 2097152; }
    float4 v = *(const float4*)(s + (size_t)off * 4);
    ushort4 o;
    o.x = f2bf(v.x); o.y = f2bf(v.y); o.z = f2bf(v.z); o.w = f2bf(v.w);
    *(ushort4*)(d + (size_t)off * 4) = o;
}

// descriptor fp32 [4096,1024] -> bf16 into cat[:, 0:1024] (ld 2048)
__global__ __launch_bounds__(256) void k_cast_desc(const float* __restrict__ in,
                                                   unsigned short* __restrict__ cat) {
    int i = (blockIdx.x * 256 + threadIdx.x) * 4;   // i < 4194304
    float4 v = *(const float4*)(in + i);
    int row = i >> 10, col = i & 1023;
    ushort4 o;
    o.x = f2bf(v.x); o.y = f2bf(v.y); o.z = f2bf(v.z); o.w = f2bf(v.w);
    *(ushort4*)(cat + (size_t)row * 2048 + col) = o;
}

// ---------------- GEMM: C[M,N] = A[M,K] * Bm[N,K]^T + bias ----------------
// m97 structure: 128x128 tile, BK=64, 4 waves, 16x16x32 bf16 MFMA, global_load_lds staging.
// EPI: 1 = bf16 store, 2 = fp32 store + residual add, 3 = qkv split-scatter (bf16)
template <int EPI>
__global__ __launch_bounds__(256) void k_gemm(const unsigned short* __restrict__ A, int lda,
                                              const unsigned short* __restrict__ Bm, int ldb,
                                              void* __restrict__ Cv, int ldc,
                                              const float* __restrict__ bias,
                                              const float* __restrict__ resid, int ldr,
                                              unsigned short* __restrict__ qd,
                                              unsigned short* __restrict__ kd,
                                              unsigned short* __restrict__ vd,
                                              int K) {
    __shared__ unsigned short As[128 * 64];
    __shared__ unsigned short Bs[128 * 64];
    const int tid  = threadIdx.x;
    const int wave = tid >> 6, lane = tid & 63;
    const int wr = wave >> 1, wc = wave & 1;
    const int brow = blockIdx.y * 128, bcol = blockIdx.x * 128;

    const int srow = (lane >> 3);        // staging row-within-8
    const int scol = (lane & 7) * 8;     // staging element offset in row
    const int frow = lane & 15;          // fragment row/col (lane&15)
    const int fk   = (lane >> 4) * 8;    // fragment k base

    f32x4 acc[4][4] = {};

    for (int kt = 0; kt < K; kt += 64) {
        __syncthreads();
#pragma unroll
        for (int j = 0; j < 4; ++j) {
            int r = wave * 32 + j * 8 + srow;
            GLDS16(A  + (size_t)(brow + r) * lda + kt + scol, (char*)As + wave * 4096 + j * 1024);
            GLDS16(Bm + (size_t)(bcol + r) * ldb + kt + scol, (char*)Bs + wave * 4096 + j * 1024);
        }
        __syncthreads();
#pragma unroll
        for (int ks = 0; ks < 2; ++ks) {
            bf16x8 a[4], b[4];
#pragma unroll
            for (int m = 0; m < 4; ++m)
                a[m] = *(const bf16x8*)(As + (wr * 64 + m * 16 + frow) * 64 + ks * 32 + fk);
#pragma unroll
            for (int n = 0; n < 4; ++n)
                b[n] = *(const bf16x8*)(Bs + (wc * 64 + n * 16 + frow) * 64 + ks * 32 + fk);
#pragma unroll
            for (int m = 0; m < 4; ++m)
#pragma unroll
                for (int n = 0; n < 4; ++n)
                    acc[m][n] = __builtin_amdgcn_mfma_f32_16x16x32_bf16(a[m], b[n], acc[m][n], 0, 0, 0);
        }
    }

    // epilogue: C/D layout col=lane&15, row=(lane>>4)*4+r
    const int orow = (lane >> 4) * 4;
#pragma unroll
    for (int m = 0; m < 4; ++m) {
        int row0 = brow + wr * 64 + m * 16 + orow;
#pragma unroll
        for (int n = 0; n < 4; ++n) {
            int col = bcol + wc * 64 + n * 16 + frow;
            float bs = bias[col];
#pragma unroll
            for (int r = 0; r < 4; ++r) {
                float v = acc[m][n][r] + bs;
                if (EPI == 3) {
                    // col in [0,3072) interpreted as h*192 + d*3 + c (H,HD,3 layout)
                    int row = row0 + r;
                    int bb = row >> 11, nr = row & (N_ - 1);
                    int h = col / 192;
                    int rem = col - h * 192;
                    int d = rem / 3;
                    int c = rem - d * 3;
                    unsigned short* dst = (c == 0) ? qd : (c == 1) ? kd : vd;
                    dst[(((size_t)(bb * H_ + h)) * N_ + nr) * 64 + d] = f2bf(v);
                } else if (EPI == 2) {
                    v += resid[(size_t)(row0 + r) * ldr + col];
                    ((float*)Cv)[(size_t)(row0 + r) * ldc + col] = v;
                } else {
                    ((unsigned short*)Cv)[(size_t)(row0 + r) * ldc + col] = f2bf(v);
                }
            }
        }
    }
}

// ---------------- in-place RoPE on Q,K (bf16), enc fp32 [2,B,H,N,HD] ----------------
// Q additionally pre-scaled by QSCALE so attention can use exp2 directly.
__global__ __launch_bounds__(256) void k_rope_ip(unsigned short* __restrict__ Qb,
                                                 unsigned short* __restrict__ Kb,
                                                 const float* __restrict__ enc) {
    int idx = blockIdx.x * 256 + threadIdx.x;   // 2^21 pair-slots
    int i  = idx & 31;                // pair within head (d = 2i, 2i+1)
    int n  = (idx >> 5) & (N_ - 1);
    int bh = idx >> 16;
    size_t eoff = ((size_t)bh * N_ + n) * 64 + i * 2;
    float2 e0 = *(const float2*)(enc + eoff);
    float2 e1 = *(const float2*)(enc + (size_t)BH_ * N_ * 64 + eoff);
    ushort2 qp = *(const ushort2*)(Qb + eoff);
    ushort2 kp = *(const ushort2*)(Kb + eoff);
    float q1 = bf2f(qp.x), q2 = bf2f(qp.y);
    float k1 = bf2f(kp.x), k2 = bf2f(kp.y);
    ushort2 qo, ko;
    qo.x = f2bf((q1 * e0.x - q2 * e1.x) * QSCALE);
    qo.y = f2bf((q2 * e0.y + q1 * e1.y) * QSCALE);
    ko.x = f2bf(k1 * e0.x - k2 * e1.x);
    ko.y = f2bf(k2 * e0.y + k1 * e1.y);
    *(ushort2*)(Qb + eoff) = qo;
    *(ushort2*)(Kb + eoff) = ko;
}

// ---------------- V transpose: [B,H,N,HD] -> [B,H,HD,N] ----------------
__global__ __launch_bounds__(256) void k_transpose_v(const unsigned short* __restrict__ Vb,
                                                     unsigned short* __restrict__ Vt) {
    __shared__ unsigned short t[64][72];   // +8 pad
    int bh = blockIdx.y, n0 = blockIdx.x * 64;
    int tid = threadIdx.x;
    int r  = tid >> 2;            // 0..63 (n_local)
    int c0 = (tid & 3) * 16;      // 16 d per thread
    const unsigned short* src = Vb + ((size_t)bh * N_ + n0 + r) * 64 + c0;
    *(bf16x8*)(&t[r][c0])     = *(const bf16x8*)(src);
    *(bf16x8*)(&t[r][c0 + 8]) = *(const bf16x8*)(src + 8);
    __syncthreads();
    int d  = tid >> 2;            // 0..63
    int nc = (tid & 3) * 16;      // 16 n per thread
    bf16x8 o0, o1;
#pragma unroll
    for (int j = 0; j < 8; ++j) { o0[j] = (short)t[nc + j][d]; o1[j] = (short)t[nc + 8 + j][d]; }
    unsigned short* dst = Vt + ((size_t)bh * 64 + d) * N_ + n0 + nc;
    *(bf16x8*)(dst)     = o0;
    *(bf16x8*)(dst + 8) = o1;
}

// ---------------- flash attention (swapped QK^T, lane-local softmax rows) --------
// grid 1024 blocks, XCD-swizzled. 4 waves x 16 q-rows, KV tile 64, double-buffered
// XOR-swizzled LDS. S computed as mfma(K,Q): S[q=lane&15][key=(lane>>4)*4+r+16kc],
// so each lane owns one q-row -> 2-shuffle reduces, packed b64 P-stores via cvt_pk.
__global__ __launch_bounds__(256) void k_attn(const unsigned short* __restrict__ Qb,
                                              const unsigned short* __restrict__ Kb,
                                              const unsigned short* __restrict__ Vt,
                                              unsigned short* __restrict__ Ctx) {
    __shared__ unsigned short Ks[2][64 * 64];  // [key][d], swizzled
    __shared__ unsigned short Vs[2][64 * 64];  // [d][key], swizzled
    __shared__ unsigned short Ps[4][16 * 64];  // per-wave P [q][key], swizzled

    // XCD-aware remap: lin%8 = XCD; give each XCD 4 whole bh (512KB K+V < 4MB L2)
    int lin = blockIdx.x + 32 * blockIdx.y;   // 0..1023
    int ixc = lin >> 3;                        // 0..127 within-XCD index
    int bh  = (lin & 7) * 4 + (ixc >> 5);
    int q0  = (ixc & 31) * 64;
    int b = bh >> 4, h = bh & 15;
    int tid = threadIdx.x, wave = tid >> 6, lane = tid & 63;
    int frow = lane & 15, fk = (lane >> 4) * 8, g = lane >> 4;
    int f7x8 = (frow & 7) * 8;                 // read-side swizzle term

    // staging: per wave 16 rows (8 lanes/row), source col pre-swizzled so that
    // LDS[row][c] = global[row][c ^ ((row&7)*8)]
    int srow = lane >> 3;                          // 0..7 == row&7
    int scol = ((lane & 7) ^ srow) * 8;            // swizzled source col (elems)

    const unsigned short* Kbh = Kb + (size_t)bh * N_ * 64;
    const unsigned short* Vbh = Vt + (size_t)bh * 64 * N_;

#define ATTN_STAGE(bufi, kt)                                                           \
    do {                                                                               \
        _Pragma("unroll")                                                              \
        for (int j = 0; j < 2; ++j) {                                                  \
            int rr = wave * 16 + j * 8 + srow;                                         \
            GLDS16(Kbh + (size_t)((kt) + rr) * 64 + scol,                              \
                   (char*)Ks[bufi] + wave * 2048 + j * 1024);                          \
            GLDS16(Vbh + (size_t)rr * N_ + (kt) + scol,                                \
                   (char*)Vs[bufi] + wave * 2048 + j * 1024);                          \
        }                                                                              \
    } while (0)

    // Q fragments in registers; used as MFMA B-operand (col=q=lane&15, k=fk+j)
    const unsigned short* qptr = Qb + ((size_t)bh * N_ + q0 + wave * 16 + frow) * 64;
    bf16x8 qf[2];
    qf[0] = *(const bf16x8*)(qptr + fk);
    qf[1] = *(const bf16x8*)(qptr + 32 + fk);

    float m = -INFINITY;   // running max for q-row = frow (lane-local)
    float l = 0.f;         // running denom for q-row = frow
    f32x4 accO[4] = {};    // O[q=g*4+r][d=df*16+frow]

    ATTN_STAGE(0, 0);

    for (int t = 0; t < N_ / 64; ++t) {
        int cur = t & 1;
        __syncthreads();                      // drains vmcnt: tile t resident
        if (t + 1 < N_ / 64) ATTN_STAGE(cur ^ 1, (t + 1) * 64);

        // S^T-mfma: st[kc] holds S[q=frow][key=g*4+r+16kc]
        f32x4 st[4];
        __builtin_amdgcn_s_setprio(1);
#pragma unroll
        for (int kc = 0; kc < 4; ++kc) {
            f32x4 a = {};
#pragma unroll
            for (int ks = 0; ks < 2; ++ks) {
                bf16x8 kfr = *(const bf16x8*)(Ks[cur] + (kc * 16 + frow) * 64 + ((ks * 32 + fk) ^ f7x8));
                a = __builtin_amdgcn_mfma_f32_16x16x32_bf16(kfr, qf[ks], a, 0, 0, 0);
            }
            st[kc] = a;
        }
        __builtin_amdgcn_s_setprio(0);

        // lane-local online softmax for q-row = frow (16 keys local, x4 lanes via g)
        float mloc = fmaxf(fmaxf(fmaxf(st[0][0], st[0][1]), fmaxf(st[0][2], st[0][3])),
                           fmaxf(fmaxf(st[1][0], st[1][1]), fmaxf(st[1][2], st[1][3])));
        mloc = fmaxf(mloc,
               fmaxf(fmaxf(fmaxf(st[2][0], st[2][1]), fmaxf(st[2][2], st[2][3])),
                     fmaxf(fmaxf(st[3][0], st[3][1]), fmaxf(st[3][2], st[3][3]))));
        mloc = fmaxf(mloc, __shfl_xor(mloc, 16));
        mloc = fmaxf(mloc, __shfl_xor(mloc, 32));
        float mn = fmaxf(m, mloc);
        float sc = exp2f(m - mn);
        m = mn;
        float ps = 0.f;
#pragma unroll
        for (int kc = 0; kc < 4; ++kc)
#pragma unroll
            for (int r = 0; r < 4; ++r) {
                float p = exp2f(st[kc][r] - mn);
                st[kc][r] = p;
                ps += p;
            }
        ps += __shfl_xor(ps, 16);
        ps += __shfl_xor(ps, 32);
        l = l * sc + ps;

        // broadcast rescale factors to accO rows (q = g*4+r lives in lane q of group 0)
        float scl[4];
#pragma unroll
        for (int r = 0; r < 4; ++r) scl[r] = __shfl(sc, g * 4 + r);
#pragma unroll
        for (int df = 0; df < 4; ++df)
#pragma unroll
            for (int r = 0; r < 4; ++r) accO[df][r] *= scl[r];

        // P store: 4 contiguous keys per kc -> cvt_pk + ds_write_b64, swizzled
#pragma unroll
        for (int kc = 0; kc < 4; ++kc) {
            unsigned lo, hi;
            asm("v_cvt_pk_bf16_f32 %0, %1, %2" : "=v"(lo) : "v"(st[kc][0]), "v"(st[kc][1]));
            asm("v_cvt_pk_bf16_f32 %0, %1, %2" : "=v"(hi) : "v"(st[kc][2]), "v"(st[kc][3]));
            int col = (kc * 16 + g * 4) ^ f7x8;
            uint2 w; w.x = lo; w.y = hi;
            *(uint2*)(&Ps[wave][frow * 64 + col]) = w;
        }
        asm volatile("s_waitcnt lgkmcnt(0)" ::: "memory");
        __builtin_amdgcn_sched_barrier(0);

        // O += P V  (pa: A-frag row=q=frow; vf: B-frag col=d)
        __builtin_amdgcn_s_setprio(1);
#pragma unroll
        for (int ks = 0; ks < 2; ++ks) {
            bf16x8 pa = *(const bf16x8*)(&Ps[wave][frow * 64 + ((ks * 32 + fk) ^ f7x8)]);
#pragma unroll
            for (int df = 0; df < 4; ++df) {
                bf16x8 vf = *(const bf16x8*)(Vs[cur] + (df * 16 + frow) * 64 + ((ks * 32 + fk) ^ f7x8));
                accO[df] = __builtin_amdgcn_mfma_f32_16x16x32_bf16(pa, vf, accO[df], 0, 0, 0);
            }
        }
        __builtin_amdgcn_s_setprio(0);
    }

    // write context into [B, N, H*HD] (bf16); accO row r is q=g*4+r -> l from lane g*4+r
    float inv[4];
#pragma unroll
    for (int r = 0; r < 4; ++r) inv[r] = 1.0f / __shfl(l, g * 4 + r);
#pragma unroll
    for (int df = 0; df < 4; ++df)
#pragma unroll
        for (int r = 0; r < 4; ++r) {
            int q = q0 + wave * 16 + g * 4 + r;
            Ctx[((size_t)(b * N_ + q)) * D_ + h * 64 + df * 16 + frow] = f2bf(accO[df][r] * inv[r]);
        }
#undef ATTN_STAGE
}

// ---------------- LayerNorm + exact GELU (per row of 2048, bf16 in/out) ----------------
__global__ __launch_bounds__(256) void k_ln_gelu(const unsigned short* __restrict__ hsrc,
                                                 const float* __restrict__ gma,
                                                 const float* __restrict__ bta,
                                                 unsigned short* __restrict__ out) {
    __shared__ float red[2][4];
    int row = blockIdx.x, tid = threadIdx.x;
    const unsigned short* hr = hsrc + (size_t)row * 2048 + tid * 8;
    bf16x8 hv = *(const bf16x8*)(hr);
    float xs[8];
    float s = 0.f, q = 0.f;
#pragma unroll
    for (int j = 0; j < 8; ++j) {
        float x = bf2f((unsigned short)hv[j]);
        xs[j] = x; s += x; q += x * x;
    }
#pragma unroll
    for (int off = 1; off < 64; off <<= 1) {
        s += __shfl_xor(s, off);
        q += __shfl_xor(q, off);
    }
    int wave = tid >> 6;
    if ((tid & 63) == 0) { red[0][wave] = s; red[1][wave] = q; }
    __syncthreads();
    s = red[0][0] + red[0][1] + red[0][2] + red[0][3];
    q = red[1][0] + red[1][1] + red[1][2] + red[1][3];
    float mu   = s * (1.f / 2048.f);
    float var  = q * (1.f / 2048.f) - mu * mu;
    float rstd = rsqrtf(var + 1e-5f);
    int c = tid * 8;
#pragma unroll
    for (int j = 0; j < 8; ++j) {
        float x = (xs[j] - mu) * rstd * gma[c + j] + bta[c + j];
        float y = 0.5f * x * (1.f + erff(x * 0.70710678118654752f));
        out[(size_t)row * 2048 + c + j] = f2bf(y);
    }
}

// ---------------- launch ----------------
extern "C" void kernel_launch(void* const* d_in, const int* in_sizes, int n_in,
                              void* d_out, int out_size, void* d_ws, size_t ws_size,
                              hipStream_t stream) {
    const float* descriptor = (const float*)d_in[0];
    const float* encoding   = (const float*)d_in[1];
    const float* w_qkv      = (const float*)d_in[2];
    const float* b_qkv      = (const float*)d_in[3];
    const float* w_out      = (const float*)d_in[4];
    const float* b_out      = (const float*)d_in[5];
    const float* w_ffn1     = (const float*)d_in[6];
    const float* b_ffn1     = (const float*)d_in[7];
    const float* ln_g       = (const float*)d_in[8];
    const float* ln_b       = (const float*)d_in[9];
    const float* w_ffn2     = (const float*)d_in[10];
    const float* b_ffn2     = (const float*)d_in[11];
    float* out = (float*)d_out;

    char* ws = (char*)d_ws;
    // Tight 62MB layout with liveness-based aliasing:
    unsigned short* wffn1_b = (unsigned short*)(ws);                        // [0,8)
    unsigned short* wffn2_b = (unsigned short*)(ws + ((size_t)8  << 20));   // [8,12)
    unsigned short* wout_b  = (unsigned short*)(ws + ((size_t)12 << 20));   // [12,14)
    unsigned short* cat     = (unsigned short*)(ws + ((size_t)14 << 20));   // [14,30) live: ->FFN1
    unsigned short* Qb      = (unsigned short*)(ws + ((size_t)30 << 20));   // [30,38) live: qkv->attn
    unsigned short* Kb      = (unsigned short*)(ws + ((size_t)38 << 20));   // [38,46)
    unsigned short* Vb      = (unsigned short*)(ws + ((size_t)46 << 20));   // [46,54) live: qkv->transpose
    unsigned short* wqkv_b  = (unsigned short*)(ws + ((size_t)54 << 20));   // [54,60) live: ->qkv gemm
    unsigned short* Vt      = (unsigned short*)(ws + ((size_t)54 << 20));   // [54,62) after qkv gemm
    unsigned short* msg     = (unsigned short*)(ws + ((size_t)46 << 20));   // over Vb (dead after transpose)
    unsigned short* hbuf    = (unsigned short*)(ws + ((size_t)30 << 20));   // over Qb/Kb (dead after attn)
    unsigned short* h2      = (unsigned short*)(ws + ((size_t)14 << 20));   // over cat (dead after FFN1)

    // 1) casts
    k_cast_desc<<<4096, 256, 0, stream>>>(descriptor, cat);
    k_cast_w4<<<10240, 256, 0, stream>>>(w_qkv, w_out, w_ffn1, w_ffn2,
                                         wqkv_b, wout_b, wffn1_b, wffn2_b);

    // 2) QKV projection with split-scatter epilogue -> Qb,Kb,Vb bf16 [B,H,N,64]
    k_gemm<3><<<dim3(24, 32), 256, 0, stream>>>(cat, 2048, wqkv_b, 1024, nullptr, 0,
                                                b_qkv, nullptr, 0, Qb, Kb, Vb, 1024);
    // 3) in-place RoPE on Q,K (Q pre-scaled by QSCALE)
    k_rope_ip<<<8192, 256, 0, stream>>>(Qb, Kb, encoding);
    // 4) V transpose -> [B,H,64,N]
    k_transpose_v<<<dim3(32, 32), 256, 0, stream>>>(Vb, Vt);
    // 5) attention -> msg bf16 [4096,1024]
    k_attn<<<dim3(32, 32), 256, 0, stream>>>(Qb, Kb, Vt, msg);
    // 6) out-proj -> bf16 into cat[:,1024:2048]
    k_gemm<1><<<dim3(8, 32), 256, 0, stream>>>(msg, 1024, wout_b, 1024, cat + 1024, 2048,
                                               b_out, nullptr, 0, nullptr, nullptr, nullptr, 1024);
    // 7) FFN1: cat [4096,2048] @ w_ffn1^T -> hbuf bf16
    k_gemm<1><<<dim3(16, 32), 256, 0, stream>>>(cat, 2048, wffn1_b, 2048, hbuf, 2048,
                                                b_ffn1, nullptr, 0, nullptr, nullptr, nullptr, 2048);
    // 8) LayerNorm + GELU -> h2 bf16
    k_ln_gelu<<<4096, 256, 0, stream>>>(hbuf, ln_g, ln_b, h2);
    // 9) FFN2 + residual -> out f32
    k_gemm<2><<<dim3(8, 32), 256, 0, stream>>>(h2, 2048, wffn2_b, 2048, out, 1024,
                                               b_ffn2, descriptor, 1024, nullptr, nullptr, nullptr, 2048);
}